// Round 9
// baseline (443.486 us; speedup 1.0000x reference)
//
#include <hip/hip_runtime.h>
#include <math.h>

#define F 32
#define K 16
#define EPSN 1e-8f
#define NPB 512   // nodes per block (8 iterations of 64)

// MFMA formulation (verified round 8: 161 us, clean traffic, absmax ok).
// Round-9 deltas:
//  - Phase-split iterations: ALL R slab gathers + next-iter index loads
//    issue before sched_barrier(0); compute (norm/cvt/MFMA) after. Forces
//    a 5-deep memory pipeline (round-8's VGPR=52 proved the compiler
//    serialized gathers to chase occupancy).
//  - NPB 256->512: halves the W-preamble amortized cost.
//
// Fragment layouts (m89-verified C/D; standard gfx950 A/B):
//   A[i][k]: lane l holds row i=l&15, k = 8*(l>>4)+e (e=0..7)
//   B[k][j]: lane l holds col j=l&15, k = 8*(l>>4)+e
//   D[i][j]: lane l holds col j=l&15, rows i = (l>>4)*4+reg
// Lane l: node = l&15, feature-slice owner kq = l>>4.
// Precision: hi/lo f16 split, 3 MFMAs (Ah.Bh + Ah.Bl + Al.Bh), err ~1e-5.

typedef _Float16 half8 __attribute__((ext_vector_type(8)));
typedef float f32x4  __attribute__((ext_vector_type(4)));

template<int DEG>
__device__ __forceinline__ void process_deg(const float* __restrict__ x,
                                            const int*   __restrict__ sel,
                                            const int*   __restrict__ nei,
                                            const float* __restrict__ Wf,
                                            const float* __restrict__ Wn,
                                            float* __restrict__ out,
                                            int nd, int i0,
                                            _Float16* sWh, _Float16* sWl)
{
    constexpr int R     = 1 + DEG;
    constexpr int NW    = K * R;
    constexpr int ITERS = NPB / 64;
    const int tid = threadIdx.x;

    // ---- preamble: normalize W rows, hi/lo split, scatter into A-layout ----
    if (tid < NW) {
        const float* src = (tid < K) ? (Wf + tid * F) : (Wn + (tid - K) * F);
        float ss = 0.f;
        #pragma unroll
        for (int f = 0; f < F; ++f) { const float t = src[f]; ss += t * t; }
        const float sc = 1.f / (sqrtf(ss) + EPSN);
        const int t = tid - K;
        const int r = (tid < K) ? 0   : (1 + t % DEG);
        const int k = (tid < K) ? tid : (t / DEG);
        #pragma unroll
        for (int f = 0; f < F; ++f) {
            const float wv = src[f] * sc;
            const _Float16 hi = (_Float16)wv;
            const _Float16 lo = (_Float16)(wv - (float)hi);
            const int off = r * 512 + (k + 16 * (f >> 3)) * 8 + (f & 7);
            sWh[off] = hi; sWl[off] = lo;
        }
    }
    __syncthreads();

    const int lane = tid & 63;
    const int wv   = tid >> 6;        // wave id 0..3
    const int jcol = lane & 15;       // node slot within the wave's 16
    const int kq   = lane >> 4;       // feature-slice / k-quartet owner
    const float invdeg = 1.f / (float)DEG;

    // iteration-0 indices (clamped: lanes stay alive for MFMA/shfl)
    int i = i0 + wv * 16 + jcol;
    int ic = (i < nd) ? i : (nd - 1);
    int node = sel[ic];
    int nn[DEG];
    #pragma unroll
    for (int j = 0; j < DEG; ++j) nn[j] = nei[ic * DEG + j];

    #pragma unroll 1
    for (int it = 0; it < ITERS; ++it) {
        // ---- phase 1: issue ALL R slab gathers ----
        float4 rv[2 * R];
        #pragma unroll
        for (int r = 0; r < R; ++r) {
            const unsigned row = (unsigned)((r == 0) ? node : nn[r - 1]);
            const float* xr = x + row * (unsigned)F + kq * 8;
            rv[2 * r]     = *(const float4*)(xr);
            rv[2 * r + 1] = *(const float4*)(xr + 4);
        }

        // next-iter index prefetch (issues alongside the gathers)
        int node_n = node;
        int nn_n[DEG];
        #pragma unroll
        for (int j = 0; j < DEG; ++j) nn_n[j] = nn[j];
        if (it + 1 < ITERS) {
            const int i2  = i0 + (it + 1) * 64 + wv * 16 + jcol;
            const int ic2 = (i2 < nd) ? i2 : (nd - 1);
            node_n = sel[ic2];
            #pragma unroll
            for (int j = 0; j < DEG; ++j) nn_n[j] = nei[ic2 * DEG + j];
        }

        // pin: everything above (loads) must issue before anything below
        __builtin_amdgcn_sched_barrier(0);

        // ---- phase 2: per slab norm + cvt + MFMA ----
        f32x4 acc = {0.f, 0.f, 0.f, 0.f};
        #pragma unroll
        for (int r = 0; r < R; ++r) {
            const float4 a0 = rv[2 * r];
            const float4 a1 = rv[2 * r + 1];

            float ss = a0.x*a0.x + a0.y*a0.y + a0.z*a0.z + a0.w*a0.w
                     + a1.x*a1.x + a1.y*a1.y + a1.z*a1.z + a1.w*a1.w;
            ss += __shfl_xor(ss, 16);    // slice-mates: l^16, l^32 share a node
            ss += __shfl_xor(ss, 32);
            float sc = 1.f / (sqrtf(ss) + EPSN);
            if (r > 0) sc *= invdeg;

            const float f0 = a0.x*sc, f1 = a0.y*sc, f2 = a0.z*sc, f3 = a0.w*sc;
            const float f4 = a1.x*sc, f5 = a1.y*sc, f6 = a1.z*sc, f7 = a1.w*sc;

            half8 bh, bl;
            bh[0]=(_Float16)f0; bl[0]=(_Float16)(f0-(float)bh[0]);
            bh[1]=(_Float16)f1; bl[1]=(_Float16)(f1-(float)bh[1]);
            bh[2]=(_Float16)f2; bl[2]=(_Float16)(f2-(float)bh[2]);
            bh[3]=(_Float16)f3; bl[3]=(_Float16)(f3-(float)bh[3]);
            bh[4]=(_Float16)f4; bl[4]=(_Float16)(f4-(float)bh[4]);
            bh[5]=(_Float16)f5; bl[5]=(_Float16)(f5-(float)bh[5]);
            bh[6]=(_Float16)f6; bl[6]=(_Float16)(f6-(float)bh[6]);
            bh[7]=(_Float16)f7; bl[7]=(_Float16)(f7-(float)bh[7]);

            const int aoff = r * 512 + lane * 8;
            const half8 ah = *(const half8*)(sWh + aoff);
            const half8 al = *(const half8*)(sWl + aoff);

            acc = __builtin_amdgcn_mfma_f32_16x16x32_f16(ah, bh, acc, 0, 0, 0);
            acc = __builtin_amdgcn_mfma_f32_16x16x32_f16(ah, bl, acc, 0, 0, 0);
            acc = __builtin_amdgcn_mfma_f32_16x16x32_f16(al, bh, acc, 0, 0, 0);
        }

        // ---- store: lane covers float4 slots b*4+kq of the 64-float row ----
        if (i0 + it * 64 + wv * 16 + jcol < nd) {
            float* orow = out + (size_t)node * (4 * K);
            #pragma unroll
            for (int b = 0; b < 4; ++b) {
                float4 vst = make_float4(0.f, 0.f, 0.f, 0.f);
                if (b == DEG - 1)
                    vst = make_float4(acc[0], acc[1], acc[2], acc[3]);
                *(float4*)(orow + (b * 4 + kq) * 4) = vst;
            }
        }

        // rotate prefetched indices (static copies, no runtime indexing)
        node = node_n;
        #pragma unroll
        for (int j = 0; j < DEG; ++j) nn[j] = nn_n[j];
    }
}

struct Args {
    const float* x;
    const int*   sel[4];
    const int*   nei[4];
    const float* Wf[4];
    const float* Wn[4];
    int nd[4];
    int bcum[4];   // cumulative block counts: after deg1, deg1+2, ...
};

// No second launch_bounds arg (rounds 1/3/4/5: forced caps below natural use
// spill catastrophically). Natural use here ~75-90 VGPR by design.
__global__ __launch_bounds__(256)
void fused_kernel(Args a, float* __restrict__ out)
{
    __shared__ __align__(16) _Float16 sWh[5 * 512];   // 5 slabs x 1 KB
    __shared__ __align__(16) _Float16 sWl[5 * 512];
    const int bid = blockIdx.x;

    if (bid < a.bcum[0]) {
        process_deg<1>(a.x, a.sel[0], a.nei[0], a.Wf[0], a.Wn[0], out,
                       a.nd[0], bid * NPB, sWh, sWl);
    } else if (bid < a.bcum[1]) {
        process_deg<2>(a.x, a.sel[1], a.nei[1], a.Wf[1], a.Wn[1], out,
                       a.nd[1], (bid - a.bcum[0]) * NPB, sWh, sWl);
    } else if (bid < a.bcum[2]) {
        process_deg<3>(a.x, a.sel[2], a.nei[2], a.Wf[2], a.Wn[2], out,
                       a.nd[2], (bid - a.bcum[1]) * NPB, sWh, sWl);
    } else {
        process_deg<4>(a.x, a.sel[3], a.nei[3], a.Wf[3], a.Wn[3], out,
                       a.nd[3], (bid - a.bcum[2]) * NPB, sWh, sWl);
    }
}

extern "C" void kernel_launch(void* const* d_in, const int* in_sizes, int n_in,
                              void* d_out, int out_size, void* d_ws, size_t ws_size,
                              hipStream_t stream)
{
    Args a;
    a.x = (const float*)d_in[0];
    for (int d = 0; d < 4; ++d) {
        a.sel[d] = (const int*)  d_in[1 + 4 * d];
        a.nei[d] = (const int*)  d_in[2 + 4 * d];
        a.Wf[d]  = (const float*)d_in[3 + 4 * d];
        a.Wn[d]  = (const float*)d_in[4 + 4 * d];
        a.nd[d]  = in_sizes[1 + 4 * d];
    }
    int cum = 0;
    for (int d = 0; d < 4; ++d) {
        cum += (a.nd[d] + NPB - 1) / NPB;
        a.bcum[d] = cum;
    }
    float* out = (float*)d_out;
    fused_kernel<<<cum, 256, 0, stream>>>(a, out);
}